// Round 7
// baseline (931.797 us; speedup 1.0000x reference)
//
#include <hip/hip_runtime.h>
#include <stdint.h>

// Problem constants
#define NROWS 16384   // B*H*W = 16*32*32
#define KENT  8192    // codebook entries
#define CDIM  256     // embedding dim
#define NELEM 4194304 // B*H*W*C elements of z / z_q

// int8 screen scales: z*22 (clamp +-127 = 5.77 sigma), cb*127*8192 (<=0.5 LSB)
#define ZSCALE 22.0f
#define ESCALE 1040384.0f      // 127*8192, exact in fp32
#define MARGIN_INT 4096        // = 1.79e-4 real ~ 8 sigma of i8-quant error
#define SBIAS 4194304          // 1<<22, |score| <= 256*127*127 = 4129024 < SBIAS

// ws layout (bytes):
//   [0,        4194304): zbi8   i8[4M]
//   [4194304,  6291456): cbi8   i8[2M]
//   [6291456, 23068672): gstats u64[128][16384]
//   [23068672,23134208): z2w   float[16384]
//   [23199744,23200000): barrier counters (3 x 128B lines), memset each launch

typedef int v4i __attribute__((ext_vector_type(4)));

__device__ inline int q8(float x, float s) {
    int v = __float2int_rn(x * s);
    return v < -127 ? -127 : (v > 127 ? 127 : v);
}
__device__ inline unsigned pk4(int a, int b, int c, int d) {
    return (a & 255) | ((b & 255) << 8) | ((c & 255) << 16) | ((d & 255) << 24);
}
__device__ inline unsigned umax_(unsigned a, unsigned b) { return a > b ? a : b; }
__device__ inline unsigned umin_(unsigned a, unsigned b) { return a < b ? a : b; }
__device__ inline void gload_lds16(const void* g, void* l) {
    __builtin_amdgcn_global_load_lds(
        (const __attribute__((address_space(1))) void*)g,
        (__attribute__((address_space(3))) void*)l, 16, 0, 0);
}

// Device-scope grid barrier for an all-resident grid (1024 blocks @ 4/CU).
// Release fence + arrive, polled acquire with backoff, acquire fence for all
// threads. Watchdog breaks a broken barrier instead of hanging the harness.
#define GRID_BLOCKS 1024u
__device__ inline void gbar(unsigned* ctr) {
    __syncthreads();
    __threadfence();                               // release prior writes
    if (threadIdx.x == 0) {
        __hip_atomic_fetch_add(ctr, 1u, __ATOMIC_RELEASE,
                               __HIP_MEMORY_SCOPE_AGENT);
        int guard = 0;
        while (__hip_atomic_load(ctr, __ATOMIC_ACQUIRE,
                                 __HIP_MEMORY_SCOPE_AGENT) < GRID_BLOCKS &&
               guard < 2000000) {
            __builtin_amdgcn_s_sleep(8);           // ~512 cy backoff
            ++guard;
        }
    }
    __syncthreads();
    __threadfence();                               // acquire for every thread
}

// Shared-memory union (40,464 B -> <=40KiB granule; 4 blocks/CU = 160 KiB):
//   P: pprt f[2][64][17] @0 (8704); s64 f[64] @8704
//   G: A panel @0 (32768)
//   F: tile f[32*257] @0 (32896); zsF f[32][32] @32896; pmax u[8][32] @36992;
//      candL u[512] @38016; thrL i[32] @40064; bestL u64[32] @40192; cnt @40448
//   L: zs2 f[256][33] @0 (33792); wsum f[4] @33792
#define SMEM_BYTES 40464

__global__ __launch_bounds__(256, 4) void vq_fused(
        const float* __restrict__ z, const float* __restrict__ cb,
        float* __restrict__ out,
        char* __restrict__ zbi8, char* __restrict__ cbbi8,
        unsigned long long* __restrict__ gstats, float* __restrict__ z2w,
        unsigned* __restrict__ bar) {
    __shared__ __align__(16) char smem[SMEM_BYTES];
    const int t = threadIdx.x;
    const int bid = blockIdx.x;
    float* loss_out = out + NELEM;
    float* out_idx  = out + NELEM + 1;

    // ================= Phase P: prep (VALIDATED r4/r6) ======================
    if (bid >= 256 && bid < 384) {   // ---- prep_cb: half-panel, 4 thr/row
        const int ppi = bid - 256;
        const int p = ppi >> 1, h = ppi & 1;
        const int r = t & 63, qh = t >> 6;
        const int row = h * 64 + r;
        char* dst = cbbi8 + p * 32768;
        const float* src = cb + (p * 128 + row) * 256;
#pragma unroll
        for (int qq = 0; qq < 4; ++qq) {
            const int q = qh * 4 + qq;
            float4 a = *(const float4*)(src + q * 16);
            float4 b = *(const float4*)(src + q * 16 + 4);
            float4 c = *(const float4*)(src + q * 16 + 8);
            float4 d = *(const float4*)(src + q * 16 + 12);
            uint4 v;
            v.x = pk4(q8(a.x,ESCALE), q8(a.y,ESCALE), q8(a.z,ESCALE), q8(a.w,ESCALE));
            v.y = pk4(q8(b.x,ESCALE), q8(b.y,ESCALE), q8(b.z,ESCALE), q8(b.w,ESCALE));
            v.z = pk4(q8(c.x,ESCALE), q8(c.y,ESCALE), q8(c.z,ESCALE), q8(c.w,ESCALE));
            v.w = pk4(q8(d.x,ESCALE), q8(d.y,ESCALE), q8(d.z,ESCALE), q8(d.w,ESCALE));
            *(uint4*)&dst[(q * 128 + row) * 16] = v;
        }
        if (ppi == 0 && t == 0) loss_out[0] = 0.f;
    } else if (bid < 256) {          // ---- prep_z: 4 thr/row (blk, jh) split
        float (*pprt)[64][17] = (float(*)[64][17])(void*)smem;
        float* s64 = (float*)(void*)(smem + 8704);
        const int r = t & 63;
        const int part = t >> 6;
        const int blk = part >> 1, jh = part & 1;
        const int n = bid * 64 + r;
        const int b = n >> 10, hw = n & 1023;
        const float* base = z + b * 262144 + hw;

        const int p = n >> 7, rp = n & 127;
        char* dst = zbi8 + p * 32768;

        float t0[16], p01[16], pr[16];
#pragma unroll
        for (int jj = 0; jj < 4; ++jj) {
            const int j = jh * 4 + jj;
            float a[16];
#pragma unroll
            for (int L = 0; L < 16; ++L)
                a[L] = base[(blk * 128 + L + 16 * j) * 1024];
            int qb[16];
#pragma unroll
            for (int L = 0; L < 16; ++L) {
                qb[L] = q8(a[L], ZSCALE);
                float sq = a[L] * a[L];
                asm volatile("" : "+v"(sq));   // forbid FMA contraction
                if (jj == 0)      t0[L] = sq;
                else if (jj == 1) p01[L] = t0[L] + sq;
                else if (jj == 2) t0[L] = sq;
                else              pr[L] = p01[L] + (t0[L] + sq);
            }
            uint4 v;
            v.x = pk4(qb[0], qb[1], qb[2], qb[3]);
            v.y = pk4(qb[4], qb[5], qb[6], qb[7]);
            v.z = pk4(qb[8], qb[9], qb[10], qb[11]);
            v.w = pk4(qb[12], qb[13], qb[14], qb[15]);
            *(uint4*)&dst[((blk * 8 + j) * 128 + rp) * 16] = v;
        }
        if (jh == 1) {
#pragma unroll
            for (int L = 0; L < 16; ++L) pprt[blk][r][L] = pr[L];
        }
        __syncthreads();
        float bs = 0.f;
        if (jh == 0) {   // combine in validated order: C = p0123 + p4567
            float C[16];
#pragma unroll
            for (int L = 0; L < 16; ++L) C[L] = pr[L] + pprt[blk][r][L];
            float t8v[8];
#pragma unroll
            for (int L = 0; L < 8; ++L) t8v[L] = C[L] + C[L + 8];
            float t4[4];
#pragma unroll
            for (int L = 0; L < 4; ++L) t4[L] = t8v[L] + t8v[L + 4];
            float t2a = t4[0] + t4[2];
            float t2b = t4[1] + t4[3];
            bs = t2a + t2b;
            if (blk == 1) s64[r] = bs;
        }
        __syncthreads();
        if (part == 0) z2w[n] = bs + s64[r];
    }

    gbar(bar);                         // ---- P -> G

    // ================= Phase G: gemm (VALIDATED r6 persistent) ==============
    {
        char* gsm = smem;
        const int w = t >> 6, l = t & 63;
        const int q4 = l >> 4, cl = l & 15;
        const int mw = w & 1, nw = w >> 1;
        const unsigned xcd = (unsigned)bid & 7u;
        const unsigned local0 = (unsigned)bid >> 3;   // [0,128)
        const unsigned vb = ((unsigned)SBIAS << 6) + (unsigned)(q4 * 4);

#pragma unroll 1
        for (int ph = 0; ph < 2; ++ph) {
            const unsigned rem = (local0 + (unsigned)ph * 128u) & 255u;
            const unsigned pm = (rem >> 4) * 8u + xcd;
            const char* Ab = zbi8 + pm * 32768u;

            __syncthreads();
#pragma unroll
            for (int u = 0; u < 8; ++u)
                gload_lds16(Ab + u * 4096 + t * 16, gsm + u * 4096 + (w << 10));

#pragma unroll 1
            for (int png = 0; png < 4; ++png) {
                const unsigned pn = (unsigned)png * 16u + (rem & 15u);
                const char* abase = cbbi8 + pn * 32768u
                                  + (q4 * 128 + mw * 64 + cl) * 16;
                v4i af[4], afn[4];
#pragma unroll
                for (int i = 0; i < 4; ++i)
                    af[i] = *(const v4i*)(abase + i * 256);

                v4i acc[4][4];
                if (png == 0) __syncthreads();   // staging drain per panel

#pragma unroll
                for (int kt = 0; kt < 4; ++kt) {
                    v4i bfl[4];
#pragma unroll
                    for (int j = 0; j < 4; ++j)
                        bfl[j] = *(const v4i*)(gsm + kt * 8192 + q4 * 2048
                                               + nw * 1024 + j * 256 + cl * 16);
                    if (kt < 3) {
#pragma unroll
                        for (int i = 0; i < 4; ++i)
                            afn[i] = *(const v4i*)(abase + (kt + 1) * 8192 + i * 256);
                    }
                    __builtin_amdgcn_s_setprio(1);
#pragma unroll
                    for (int i = 0; i < 4; ++i)
#pragma unroll
                        for (int j = 0; j < 4; ++j) {
                            if (kt == 0)
                                acc[i][j] = __builtin_amdgcn_mfma_i32_16x16x64_i8(
                                    af[i], bfl[j], (v4i)0, 0, 0, 0);
                            else
                                acc[i][j] = __builtin_amdgcn_mfma_i32_16x16x64_i8(
                                    af[i], bfl[j], acc[i][j], 0, 0, 0);
                        }
                    __builtin_amdgcn_s_setprio(0);
#pragma unroll
                    for (int i = 0; i < 4; ++i) af[i] = afn[i];
                }

                unsigned long long* gs = gstats
                    + (pn * 2 + (unsigned)mw) * 16384u
                    + pm * 128u + (unsigned)(nw * 64);
#pragma unroll
                for (int jj = 0; jj < 4; ++jj) {
                    unsigned m1[8], m2[8];
#pragma unroll
                    for (int i = 0; i < 4; ++i)
#pragma unroll
                        for (int gp2 = 0; gp2 < 2; ++gp2) {
                            unsigned pa = ((unsigned)acc[i][jj][2 * gp2] << 6)
                                          + vb + (unsigned)(i * 16 + 2 * gp2);
                            unsigned pb = ((unsigned)acc[i][jj][2 * gp2 + 1] << 6)
                                          + vb + (unsigned)(i * 16 + 2 * gp2 + 1);
                            m1[i * 2 + gp2] = umax_(pa, pb);
                            m2[i * 2 + gp2] = umin_(pa, pb);
                        }
#pragma unroll
                    for (int s = 4; s >= 1; s >>= 1)
#pragma unroll
                        for (int u = 0; u < 4; ++u) {
                            if (u < s) {
                                unsigned a1 = m1[u], a2 = m2[u];
                                unsigned b1 = m1[u + s], b2 = m2[u + s];
                                m1[u] = umax_(a1, b1);
                                m2[u] = umax_(umin_(a1, b1), umax_(a2, b2));
                            }
                        }
                    unsigned t1 = m1[0], t2 = m2[0];
#pragma unroll
                    for (int off = 16; off <= 32; off <<= 1) {
                        unsigned o1 = (unsigned)__shfl_xor((int)t1, off);
                        unsigned o2 = (unsigned)__shfl_xor((int)t2, off);
                        t2 = umax_(umax_(t2, o2), umin_(t1, o1));
                        t1 = umax_(t1, o1);
                    }
                    if (q4 == 0)
                        gs[jj * 16 + cl] =
                            ((unsigned long long)t1 << 32) | (unsigned long long)t2;
                }
            }
        }
    }

    gbar(bar + 32);                    // ---- G -> F

    // ================= Phase F: finalize (VALIDATED r4 logic) ===============
    if (bid < 512) {
        float* tile = (float*)(void*)smem;                         // 32*257
        float (*zsF)[32] = (float(*)[32])(void*)(smem + 32896);
        unsigned (*pmaxF)[32] = (unsigned(*)[32])(void*)(smem + 36992);
        unsigned* candL = (unsigned*)(void*)(smem + 38016);
        int* thrL = (int*)(void*)(smem + 40064);
        unsigned long long* bestL = (unsigned long long*)(void*)(smem + 40192);
        unsigned* blkcnt = (unsigned*)(void*)(smem + 40448);

        const int n0 = bid * 32;
        const int b = bid >> 5, j = bid & 31;
        const int hw0 = j * 32;
        const int r = t & 31, gc = t >> 5;   // gc in [0,8): 16 groups each

        const unsigned long long* gp =
            gstats + (size_t)(gc * 16) * 16384u + (unsigned)(n0 + r);
        unsigned m = 0;
#pragma unroll 8
        for (int g2 = 0; g2 < 16; ++g2)
            m = umax_(m, (unsigned)(gp[(size_t)g2 * 16384u] >> 32));
        pmaxF[gc][r] = m;
        if (t == 0) *blkcnt = 0;
        __syncthreads();
        if (t < 32) {
            unsigned mm = 0;
#pragma unroll
            for (int g = 0; g < 8; ++g) mm = umax_(mm, pmaxF[g][t]);
            thrL[t] = (int)(mm >> 6) - MARGIN_INT;
            bestL[t] = ~0ull;
        }
        __syncthreads();

        {
            int th = thrL[r];
#pragma unroll 4
            for (int g2 = 0; g2 < 16; ++g2) {
                unsigned long long e = gp[(size_t)g2 * 16384u];
                unsigned p1 = (unsigned)(e >> 32), p2 = (unsigned)e;
                unsigned kb = (unsigned)(gc * 16 + g2) * 64u;
                if ((int)(p1 >> 6) >= th) {
                    unsigned pos = atomicAdd(blkcnt, 1u);
                    if (pos < 512u)
                        candL[pos] = ((unsigned)r << 13) | (kb + (p1 & 63u));
                }
                if ((int)(p2 >> 6) >= th) {
                    unsigned pos = atomicAdd(blkcnt, 1u);
                    if (pos < 512u)
                        candL[pos] = ((unsigned)r << 13) | (kb + (p2 & 63u));
                }
            }
        }
        __syncthreads();
        int ns = (int)(*blkcnt < 512u ? *blkcnt : 512u);

        for (int base = 0; base < ns; base += 256) {
            bool active = base + t < ns;
            int rr0 = 0, k = 0;
            if (active) {
                unsigned v = candL[base + t];
                rr0 = v >> 13; k = v & 8191;
            }
            float sacc = 0.f;
            for (int ch = 0; ch < 8; ++ch) {
                __syncthreads();
                {   // stage 32 channels x 32 rows, coalesced
                    int rr = t & 31, cc2 = t >> 5;
#pragma unroll
                    for (int u = 0; u < 4; ++u) {
                        int cc = u * 8 + cc2;
                        zsF[cc][rr] = z[b * 262144 + (ch * 32 + cc) * 1024 + hw0 + rr];
                    }
                }
                __syncthreads();
                if (active) {
                    const float4* cbp = (const float4*)(cb + k * 256 + ch * 32);
                    float4 A0 = cbp[0], A1 = cbp[1], A2 = cbp[2], A3 = cbp[3];
                    float4 A4 = cbp[4], A5 = cbp[5], A6 = cbp[6], A7 = cbp[7];
                    float Af[32] = {A0.x,A0.y,A0.z,A0.w, A1.x,A1.y,A1.z,A1.w,
                                    A2.x,A2.y,A2.z,A2.w, A3.x,A3.y,A3.z,A3.w,
                                    A4.x,A4.y,A4.z,A4.w, A5.x,A5.y,A5.z,A5.w,
                                    A6.x,A6.y,A6.z,A6.w, A7.x,A7.y,A7.z,A7.w};
#pragma unroll
                    for (int u = 0; u < 32; ++u)
                        sacc = __builtin_fmaf(zsF[u][rr0], Af[u], sacc);
                }
            }
            if (active) {
                float d = z2w[n0 + rr0] - 2.0f * sacc;
                unsigned long long key =
                    ((unsigned long long)__float_as_uint(d) << 32) | (unsigned)k;
                atomicMin(&bestL[rr0], key);
            }
        }
        __syncthreads();
        if (t < 32)
            out_idx[n0 + t] = (float)(unsigned)(bestL[t] & 0xFFFFFFFFu);

        {   // fused scatter
            const int c0 = t & 63;
            const int w0 = (t >> 6) * 8;
#pragma unroll
            for (int it = 0; it < 8; ++it) {
                int wr = w0 + it;
                int kk = (int)(unsigned)(bestL[wr] & 0xFFFFFFFFu);
                const float* src = cb + kk * 256 + c0;
                float* drow = tile + wr * 257 + c0;
                drow[0]   = src[0];
                drow[64]  = src[64];
                drow[128] = src[128];
                drow[192] = src[192];
            }
        }
        __syncthreads();

        float* obase = out + b * 262144 + j * 256;
        const int wv = t >> 3, cb8 = (t & 7) * 32;
#pragma unroll
        for (int it = 0; it < 32; ++it)
            obase[it * 8192 + t] = tile[wv * 257 + cb8 + it];
    }

    gbar(bar + 64);                    // ---- F -> L

    // ================= Phase L: loss (VALIDATED) ============================
    if (bid < 512) {
        float (*zs2)[33] = (float(*)[33])(void*)smem;
        float* wsum = (float*)(void*)(smem + 33792);
        const int b = bid >> 5, i = bid & 31;

#pragma unroll
        for (int it = 0; it < 32; ++it) {
            int k = it * 8 + (t >> 5);
            zs2[k][t & 31] = z[b * 262144 + k * 1024 + i * 32 + (t & 31)];
        }
        __syncthreads();

        const float* ob = out + b * 262144 + i * 8192;
        float lsum = 0.f;
#pragma unroll 4
        for (int it = 0; it < 32; ++it) {
            float d = zs2[t][it] - ob[it * 256 + t];
            lsum = __builtin_fmaf(d, d, lsum);
        }
#pragma unroll
        for (int off = 32; off >= 1; off >>= 1) lsum += __shfl_down(lsum, off, 64);
        int lane = t & 63, wv = t >> 6;
        if (lane == 0) wsum[wv] = lsum;
        __syncthreads();
        if (t == 0)
            atomicAdd(loss_out, (wsum[0] + wsum[1] + wsum[2] + wsum[3]) *
                                (1.25f / (float)NELEM));
    }
}

// ---------------------------------------------------------------------------
extern "C" void kernel_launch(void* const* d_in, const int* in_sizes, int n_in,
                              void* d_out, int out_size, void* d_ws, size_t ws_size,
                              hipStream_t stream) {
    const float* z  = (const float*)d_in[0];
    const float* cb = (const float*)d_in[1];
    float* out = (float*)d_out;

    char* ws = (char*)d_ws;
    char* zbi8               = ws;                                   // 4 MB
    char* cbbi8              = ws + 4194304;                         // 2 MB
    unsigned long long* gstats = (unsigned long long*)(ws + 6291456); // 16 MB
    float* z2w               = (float*)(ws + 23068672);
    unsigned* bar            = (unsigned*)(ws + 23199744);           // 3 ctrs

    hipMemsetAsync(bar, 0, 256, stream);

    vq_fused<<<1024, 256, 0, stream>>>(z, cb, out, zbi8, cbbi8,
                                       gstats, z2w, bar);
}

// Round 8
// 152.676 us; speedup vs baseline: 6.1031x; 6.1031x over previous
//
#include <hip/hip_runtime.h>
#include <stdint.h>

// Problem constants
#define NROWS 16384   // B*H*W = 16*32*32
#define KENT  8192    // codebook entries
#define CDIM  256     // embedding dim
#define NELEM 4194304 // B*H*W*C elements of z / z_q

// int8 screen scales: z*22 (clamp +-127 = 5.77 sigma), cb*127*8192 (<=0.5 LSB)
#define ZSCALE 22.0f
#define ESCALE 1040384.0f      // 127*8192, exact in fp32
#define MARGIN_INT 4096        // = 1.79e-4 real ~ 8 sigma of i8-quant error
#define SBIAS 4194304          // 1<<22, |score| <= 256*127*127 = 4129024 < SBIAS

// ws layout (bytes):
//   [0,        4194304): zbi8   i8[4M]   z int8, k-major tile layout
//   [4194304,  6291456): cbi8   i8[2M]   codebook int8, same layout
//   [6291456, 23068672): gstats u64[128][16384]  per (64-entry cb group, row):
//                        (top1 << 32) | top2, packed (score+SBIAS)<<6 | col6
//   [23068672,23134208): z2w   float[16384]  np-tree row norms

typedef int v4i __attribute__((ext_vector_type(4)));

__device__ inline int q8(float x, float s) {
    int v = __float2int_rn(x * s);
    return v < -127 ? -127 : (v > 127 ? 127 : v);
}
__device__ inline unsigned pk4(int a, int b, int c, int d) {
    return (a & 255) | ((b & 255) << 8) | ((c & 255) << 16) | ((d & 255) << 24);
}
__device__ inline unsigned umax_(unsigned a, unsigned b) { return a > b ? a : b; }
__device__ inline unsigned umin_(unsigned a, unsigned b) { return a < b ? a : b; }
__device__ inline void gload_lds16(const void* g, void* l) {
    __builtin_amdgcn_global_load_lds(
        (const __attribute__((address_space(1))) void*)g,
        (__attribute__((address_space(3))) void*)l, 16, 0, 0);
}

// ---------------------------------------------------------------------------
// Prep v3 -- 2x the occupancy of v2 (768 blocks = 3/CU, 12 waves/CU; v2 was
// 1.5/CU and HBM-latency-bound at 64 loads/thread). Same VALIDATED np-tree
// association, now 8 threads/row (one j-PAIR each):
//   p01_jp = sq(2jp) + sq(2jp+1);  p0123 = p01_0 + p01_1;
//   p4567 = p01_2 + p01_3;  C = p0123 + p4567   (identical parenthesization)
// blocks 0..511  = prep_z (32 rows/block); 512..767 = prep_cb (32 rows/block,
// q-pair per thread).
__global__ __launch_bounds__(256) void vq_prep(
        const float* __restrict__ z, const float* __restrict__ cb,
        float* __restrict__ z2w, char* __restrict__ zbi8,
        char* __restrict__ cbbi8, float* __restrict__ loss_out) {
    const int t = threadIdx.x;
    const int bid = blockIdx.x;

    if (bid >= 512) {   // ---- prep_cb: 32 rows/block, 8 thr/row (q-pair)
        const int ppi = bid - 512;            // [0,256)
        const int r5 = t & 31, qp = t >> 5;   // row-in-block, q-pair
        const int row = ppi * 32 + r5;        // cb row [0,8192)
        const int p = row >> 7, rowp = row & 127;
        char* dst = cbbi8 + p * 32768;
        const float* src = cb + row * 256;
#pragma unroll
        for (int qq = 0; qq < 2; ++qq) {
            const int q = qp * 2 + qq;
            float4 a = *(const float4*)(src + q * 16);
            float4 b = *(const float4*)(src + q * 16 + 4);
            float4 c = *(const float4*)(src + q * 16 + 8);
            float4 d = *(const float4*)(src + q * 16 + 12);
            uint4 v;
            v.x = pk4(q8(a.x,ESCALE), q8(a.y,ESCALE), q8(a.z,ESCALE), q8(a.w,ESCALE));
            v.y = pk4(q8(b.x,ESCALE), q8(b.y,ESCALE), q8(b.z,ESCALE), q8(b.w,ESCALE));
            v.z = pk4(q8(c.x,ESCALE), q8(c.y,ESCALE), q8(c.z,ESCALE), q8(c.w,ESCALE));
            v.w = pk4(q8(d.x,ESCALE), q8(d.y,ESCALE), q8(d.z,ESCALE), q8(d.w,ESCALE));
            *(uint4*)&dst[(q * 128 + rowp) * 16] = v;
        }
        if (ppi == 0 && t == 0) loss_out[0] = 0.f;
        return;
    }

    // ---- prep_z: 32 rows/block; part = (blk c-half, jp j-pair)
    __shared__ float pp[2][4][32][17];   // p01 partials, padded
    __shared__ float s32[32];
    const int r = t & 31;
    const int part = t >> 5;             // [0,8)
    const int blk = part >> 2, jp = part & 3;
    const int n = bid * 32 + r;
    const int b = n >> 10, hw = n & 1023;
    const float* base = z + b * 262144 + hw;

    const int p = n >> 7, rp = n & 127;
    char* dst = zbi8 + p * 32768;

    float t0[16], p01[16];

#pragma unroll
    for (int jj2 = 0; jj2 < 2; ++jj2) {
        const int j = jp * 2 + jj2;
        float a[16];
#pragma unroll
        for (int L = 0; L < 16; ++L)
            a[L] = base[(blk * 128 + L + 16 * j) * 1024];
        int qb[16];
#pragma unroll
        for (int L = 0; L < 16; ++L) {
            qb[L] = q8(a[L], ZSCALE);
            float sq = a[L] * a[L];
            asm volatile("" : "+v"(sq));   // forbid FMA contraction into adds
            if (jj2 == 0) t0[L] = sq;
            else          p01[L] = t0[L] + sq;   // sq_even + sq_odd
        }
        uint4 v;
        v.x = pk4(qb[0], qb[1], qb[2], qb[3]);
        v.y = pk4(qb[4], qb[5], qb[6], qb[7]);
        v.z = pk4(qb[8], qb[9], qb[10], qb[11]);
        v.w = pk4(qb[12], qb[13], qb[14], qb[15]);
        *(uint4*)&dst[((blk * 8 + j) * 128 + rp) * 16] = v;
    }

#pragma unroll
    for (int L = 0; L < 16; ++L) pp[blk][jp][r][L] = p01[L];
    __syncthreads();
    float bs = 0.f;
    if (jp == 0) {   // combine in the VALIDATED order
        float C[16];
#pragma unroll
        for (int L = 0; L < 16; ++L) {
            float p0123 = pp[blk][0][r][L] + pp[blk][1][r][L];
            float p4567 = pp[blk][2][r][L] + pp[blk][3][r][L];
            C[L] = p0123 + p4567;
        }
        float t8[8];
#pragma unroll
        for (int L = 0; L < 8; ++L) t8[L] = C[L] + C[L + 8];
        float t4[4];
#pragma unroll
        for (int L = 0; L < 4; ++L) t4[L] = t8[L] + t8[L + 4];
        float t2a = t4[0] + t4[2];
        float t2b = t4[1] + t4[3];
        bs = t2a + t2b;
        if (blk == 1) s32[r] = bs;
    }
    __syncthreads();
    if (part == 0) z2w[n] = bs + s32[r];   // bs(blk0) + bs(blk1), v1 order
}

// ---------------------------------------------------------------------------
// int8 MFMA screen v8 (VALIDATED r4, 45.5us): one-panel structure (grid 8192,
// whole z panel in LDS, ONE staging drain, 1-deep cb prefetch from L2),
// swapped operands mfma(cb, z) so each z-row's 64 scores are lane-local;
// top-2 = register tree + 2 shfl. Fits the 128-reg unified cap of (256,4):
// 64 AGPR + 64 VGPR (r2's 4-panel spilled; r6's persistence lost occupancy --
// do NOT widen or persist).
__global__ __launch_bounds__(256, 4) void vq_gemm(
        const char* __restrict__ zbi8,
        const char* __restrict__ cbbi8,
        unsigned long long* __restrict__ gstats) {
    __shared__ __align__(16) char smem[32768];   // z panel

    const int tid = threadIdx.x;
    const int w = tid >> 6, l = tid & 63;
    const int q4 = l >> 4, cl = l & 15;
    const int mw = w & 1, nw = w >> 1;   // mw: cb 64-half, nw: z 64-half

    // XCD-locality swizzle (validated r5): 16 pm x phased 16 pn per XCD
    const unsigned bx = blockIdx.x;
    const unsigned xcd = bx & 7, local = bx >> 3;
    const unsigned png = local >> 8;
    const unsigned rem = local & 255;
    const unsigned pm = (rem >> 4) * 8 + xcd;
    const unsigned pn = png * 16 + (rem & 15);

    const char* Ab = zbi8 + pm * 32768;
    const char* Bb = cbbi8 + pn * 32768;

    // stage whole z panel: 8 issues x 256 thr x 16B = 32KB
#pragma unroll
    for (int u = 0; u < 8; ++u)
        gload_lds16(Ab + u * 4096 + tid * 16, smem + u * 4096 + (w << 10));

    // cb fragments (MFMA A operand) streamed from L2: row = mw*64+i*16+cl,
    // kchunk = kt*4+q4; i via +256, kt via +8192
    const char* abase = Bb + (q4 * 128 + mw * 64 + cl) * 16;
    v4i af[4], afn[4];
#pragma unroll
    for (int i = 0; i < 4; ++i)
        af[i] = *(const v4i*)(abase + i * 256);

    const unsigned vb = ((unsigned)SBIAS << 6) + (unsigned)(q4 * 4);

    v4i acc[4][4];
    __syncthreads();   // single staging drain (af prologue rides along)

#pragma unroll
    for (int kt = 0; kt < 4; ++kt) {
        v4i bfl[4];
#pragma unroll
        for (int j = 0; j < 4; ++j)
            bfl[j] = *(const v4i*)(smem + kt * 8192 + q4 * 2048
                                        + nw * 1024 + j * 256 + cl * 16);
        if (kt < 3) {
#pragma unroll
            for (int i = 0; i < 4; ++i)
                afn[i] = *(const v4i*)(abase + (kt + 1) * 8192 + i * 256);
        }
        __builtin_amdgcn_s_setprio(1);
#pragma unroll
        for (int i = 0; i < 4; ++i)
#pragma unroll
            for (int j = 0; j < 4; ++j) {
                if (kt == 0)
                    acc[i][j] = __builtin_amdgcn_mfma_i32_16x16x64_i8(
                        af[i], bfl[j], (v4i)0, 0, 0, 0);
                else
                    acc[i][j] = __builtin_amdgcn_mfma_i32_16x16x64_i8(
                        af[i], bfl[j], acc[i][j], 0, 0, 0);
            }
        __builtin_amdgcn_s_setprio(0);
#pragma unroll
        for (int i = 0; i < 4; ++i) af[i] = afn[i];
    }

    // ---- epilogue: per z-row lane-local top-2 over this wave's 64 cb -----
    // acc[i][j][g]: cb = mw*64 + i*16 + q4*4 + g, z-row = nw*64 + j*16 + cl
    unsigned long long* gs = gstats + (pn * 2 + (unsigned)mw) * 16384u
                                    + pm * 128u + (unsigned)(nw * 64);
#pragma unroll
    for (int jj = 0; jj < 4; ++jj) {
        unsigned m1[8], m2[8];
#pragma unroll
        for (int i = 0; i < 4; ++i)
#pragma unroll
            for (int gp = 0; gp < 2; ++gp) {
                unsigned pa = ((unsigned)acc[i][jj][2 * gp] << 6)
                              + vb + (unsigned)(i * 16 + 2 * gp);
                unsigned pb = ((unsigned)acc[i][jj][2 * gp + 1] << 6)
                              + vb + (unsigned)(i * 16 + 2 * gp + 1);
                m1[i * 2 + gp] = umax_(pa, pb);
                m2[i * 2 + gp] = umin_(pa, pb);
            }
#pragma unroll
        for (int s = 4; s >= 1; s >>= 1)
#pragma unroll
            for (int u = 0; u < 4; ++u) {
                if (u < s) {
                    unsigned a1 = m1[u], a2 = m2[u];
                    unsigned b1 = m1[u + s], b2 = m2[u + s];
                    m1[u] = umax_(a1, b1);
                    m2[u] = umax_(umin_(a1, b1), umax_(a2, b2));
                }
            }
        unsigned t1 = m1[0], t2 = m2[0];
#pragma unroll
        for (int off = 16; off <= 32; off <<= 1) {
            unsigned o1 = (unsigned)__shfl_xor((int)t1, off);
            unsigned o2 = (unsigned)__shfl_xor((int)t2, off);
            t2 = umax_(umax_(t2, o2), umin_(t1, o1));
            t1 = umax_(t1, o1);
        }
        if (q4 == 0)
            gs[jj * 16 + cl] =
                ((unsigned long long)t1 << 32) | (unsigned long long)t2;
    }
}

// ---------------------------------------------------------------------------
// Finalize v3 (VALIDATED r6): rescore + scatter fused, z tile staged ONCE as
// zs[256][32]; barrier-free candidate loop; serial-FMA chain preserved.
__global__ __launch_bounds__(256) void vq_finalize(
        const float* __restrict__ z, const float* __restrict__ cb,
        const float* __restrict__ z2w,
        const unsigned long long* __restrict__ gstats,
        float* __restrict__ out, float* __restrict__ out_idx) {
    __shared__ float zs[256][32];      // [c][r], 32 KB
    __shared__ unsigned pmax[8][32];
    __shared__ int thrL[32];
    __shared__ unsigned candL[512];    // (r<<13)|k
    __shared__ unsigned blkcnt;
    __shared__ unsigned long long bestL[32];
    __shared__ float tile[32 * 257];   // scatter tile, stride 257 floats

    const int t = threadIdx.x;
    const int bid = blockIdx.x;
    const int n0 = bid * 32;
    const int b = bid >> 5, j = bid & 31;
    const int hw0 = j * 32;
    const int r = t & 31, gc = t >> 5;   // gc in [0,8): 16 groups each

    // stage z once: 256 channels x 32 rows, coalesced (128B per 32 lanes)
    {
        const int rr = t & 31, cc2 = t >> 5;
#pragma unroll
        for (int u = 0; u < 32; ++u) {
            int cc = u * 8 + cc2;
            zs[cc][rr] = z[b * 262144 + cc * 1024 + hw0 + rr];
        }
    }

    // phase 1: per-row max of group top1s (= exact global row max); keep e[]
    unsigned long long e[16];
    unsigned m = 0;
#pragma unroll
    for (int g2 = 0; g2 < 16; ++g2) {
        e[g2] = gstats[(size_t)(gc * 16 + g2) * 16384u + (unsigned)(n0 + r)];
        m = umax_(m, (unsigned)(e[g2] >> 32));
    }
    pmax[gc][r] = m;
    if (t == 0) blkcnt = 0;
    __syncthreads();
    if (t < 32) {
        unsigned mm = 0;
#pragma unroll
        for (int g = 0; g < 8; ++g) mm = umax_(mm, pmax[g][t]);
        thrL[t] = (int)(mm >> 6) - MARGIN_INT;   // biased domain both sides
        bestL[t] = ~0ull;
    }
    __syncthreads();

    // phase 2: candidates = group top-1/top-2 entries >= threshold
    {
        int th = thrL[r];
#pragma unroll
        for (int g2 = 0; g2 < 16; ++g2) {
            unsigned p1 = (unsigned)(e[g2] >> 32), p2 = (unsigned)e[g2];
            unsigned kb = (unsigned)(gc * 16 + g2) * 64u;
            if ((int)(p1 >> 6) >= th) {
                unsigned pos = atomicAdd(&blkcnt, 1u);
                if (pos < 512u)
                    candL[pos] = ((unsigned)r << 13) | (kb + (p1 & 63u));
            }
            if ((int)(p2 >> 6) >= th) {
                unsigned pos = atomicAdd(&blkcnt, 1u);
                if (pos < 512u)
                    candL[pos] = ((unsigned)r << 13) | (kb + (p2 & 63u));
            }
        }
    }
    __syncthreads();
    int ns = (int)(blkcnt < 512u ? blkcnt : 512u);

    // rescore: barrier-free candidate loop against the staged zs tile
    for (int base = 0; base < ns; base += 256) {
        if (base + t < ns) {
            unsigned v = candL[base + t];
            int rr0 = v >> 13, k = v & 8191;
            float sacc = 0.f;
#pragma unroll 1
            for (int ch = 0; ch < 8; ++ch) {
                const float4* cbp = (const float4*)(cb + k * 256 + ch * 32);
                float4 A0 = cbp[0], A1 = cbp[1], A2 = cbp[2], A3 = cbp[3];
                float4 A4 = cbp[4], A5 = cbp[5], A6 = cbp[6], A7 = cbp[7];
                float Af[32] = {A0.x,A0.y,A0.z,A0.w, A1.x,A1.y,A1.z,A1.w,
                                A2.x,A2.y,A2.z,A2.w, A3.x,A3.y,A3.z,A3.w,
                                A4.x,A4.y,A4.z,A4.w, A5.x,A5.y,A5.z,A5.w,
                                A6.x,A6.y,A6.z,A6.w, A7.x,A7.y,A7.z,A7.w};
#pragma unroll
                for (int u = 0; u < 32; ++u)
                    sacc = __builtin_fmaf(zs[ch * 32 + u][rr0], Af[u], sacc);
            }
            float d = z2w[n0 + rr0] - 2.0f * sacc;   // single rounding, d > 0
            unsigned long long key =
                ((unsigned long long)__float_as_uint(d) << 32) | (unsigned)k;
            atomicMin(&bestL[rr0], key);
        }
    }
    __syncthreads();
    if (t < 32)
        out_idx[n0 + t] = (float)(unsigned)(bestL[t] & 0xFFFFFFFFu);

    // ---- fused scatter: gather 32 winning cb rows, write out k-coalesced --
    {
        const int c0 = t & 63;
        const int w0 = (t >> 6) * 8;
#pragma unroll
        for (int it = 0; it < 8; ++it) {
            int wr = w0 + it;
            int kk = (int)(unsigned)(bestL[wr] & 0xFFFFFFFFu);
            const float* src = cb + kk * 256 + c0;
            float* drow = tile + wr * 257 + c0;
            drow[0]   = src[0];
            drow[64]  = src[64];
            drow[128] = src[128];
            drow[192] = src[192];
        }
    }
    __syncthreads();

    float* obase = out + b * 262144 + j * 256;
    const int wv = t >> 3, cb8 = (t & 7) * 32;
#pragma unroll
    for (int it = 0; it < 32; ++it)     // it = i; lane = k (coalesced store)
        obase[it * 8192 + t] = tile[wv * 257 + cb8 + it];
}

// ---------------------------------------------------------------------------
// Loss v2: split-j -- 1024 blocks (b, i, j-half), 2x occupancy of v1, 17 KB
// LDS. Pairing unchanged: zs[k][w] = z[b,k,i,jh*16+w] vs out[b,i,j,k].
// Summation regrouping is safe: atomic accumulation order was already
// nondeterministic and the loss threshold is loose.
__global__ __launch_bounds__(256) void vq_loss(
        const float* __restrict__ z, const float* __restrict__ out,
        float* __restrict__ loss_out) {
    __shared__ float zs[256][17];
    __shared__ float wsum[4];

    const int t = threadIdx.x;
    const int bid = blockIdx.x;
    const int b = bid >> 6, rest = bid & 63;
    const int i = rest >> 1, jh = rest & 1;

#pragma unroll
    for (int it = 0; it < 16; ++it) {
        int k = it * 16 + (t >> 4);
        zs[k][t & 15] = z[b * 262144 + k * 1024 + i * 32 + jh * 16 + (t & 15)];
    }
    __syncthreads();

    const float* ob = out + b * 262144 + i * 8192 + jh * 16 * 256;
    float lsum = 0.f;
#pragma unroll 4
    for (int it = 0; it < 16; ++it) {   // it = local j; lane = k
        float d = zs[t][it] - ob[it * 256 + t];
        lsum = __builtin_fmaf(d, d, lsum);
    }
#pragma unroll
    for (int off = 32; off >= 1; off >>= 1) lsum += __shfl_down(lsum, off, 64);
    int lane = t & 63, wv = t >> 6;
    if (lane == 0) wsum[wv] = lsum;
    __syncthreads();
    if (t == 0)
        atomicAdd(loss_out, (wsum[0] + wsum[1] + wsum[2] + wsum[3]) *
                            (1.25f / (float)NELEM));
}

// ---------------------------------------------------------------------------
extern "C" void kernel_launch(void* const* d_in, const int* in_sizes, int n_in,
                              void* d_out, int out_size, void* d_ws, size_t ws_size,
                              hipStream_t stream) {
    const float* z  = (const float*)d_in[0];
    const float* cb = (const float*)d_in[1];
    float* out = (float*)d_out;

    char* ws = (char*)d_ws;
    char* zbi8               = ws;                                   // 4 MB
    char* cbbi8              = ws + 4194304;                         // 2 MB
    unsigned long long* gstats = (unsigned long long*)(ws + 6291456); // 16 MB
    float* z2w               = (float*)(ws + 23068672);

    vq_prep<<<768, 256, 0, stream>>>(z, cb, z2w, zbi8, cbbi8, out + NELEM);

    vq_gemm<<<8192, 256, 0, stream>>>(zbi8, cbbi8, gstats);

    vq_finalize<<<512, 256, 0, stream>>>(z, cb, z2w, gstats,
                                         out, out + NELEM + 1);

    vq_loss<<<1024, 256, 0, stream>>>(z, out, out + NELEM);
}

// Round 9
// 149.416 us; speedup vs baseline: 6.2362x; 1.0218x over previous
//
#include <hip/hip_runtime.h>
#include <stdint.h>

// Problem constants
#define NROWS 16384   // B*H*W = 16*32*32
#define KENT  8192    // codebook entries
#define CDIM  256     // embedding dim
#define NELEM 4194304 // B*H*W*C elements of z / z_q

// int8 screen scales: z*22 (clamp +-127 = 5.77 sigma), cb*127*8192 (<=0.5 LSB)
#define ZSCALE 22.0f
#define ESCALE 1040384.0f      // 127*8192, exact in fp32
#define MARGIN_INT 4096        // = 1.79e-4 real ~ 8 sigma of i8-quant error
#define SBIAS 4194304          // 1<<22, |score| <= 256*127*127 = 4129024 < SBIAS

// ws layout (bytes):
//   [0,        4194304): zbi8   i8[4M]   z int8, k-major tile layout
//   [4194304,  6291456): cbi8   i8[2M]   codebook int8, same layout
//   [6291456, 23068672): gstats u64[128][16384]  per (64-entry cb group, row):
//                        (top1 << 32) | top2, packed (score+SBIAS)<<6 | col6
//   [23068672,23134208): z2w   float[16384]  np-tree row norms

typedef int v4i __attribute__((ext_vector_type(4)));

__device__ inline int q8(float x, float s) {
    int v = __float2int_rn(x * s);
    return v < -127 ? -127 : (v > 127 ? 127 : v);
}
__device__ inline unsigned pk4(int a, int b, int c, int d) {
    return (a & 255) | ((b & 255) << 8) | ((c & 255) << 16) | ((d & 255) << 24);
}
__device__ inline unsigned umax_(unsigned a, unsigned b) { return a > b ? a : b; }
__device__ inline unsigned umin_(unsigned a, unsigned b) { return a < b ? a : b; }
__device__ inline void gload_lds16(const void* g, void* l) {
    __builtin_amdgcn_global_load_lds(
        (const __attribute__((address_space(1))) void*)g,
        (__attribute__((address_space(3))) void*)l, 16, 0, 0);
}

// ---------------------------------------------------------------------------
// Fused prep v2 (VALIDATED r4/r6, best measured total): blocks 0..255 =
// prep_z (np-tree z2 + i8 tile, 4 thr/row), blocks 256..383 = prep_cb.
__global__ __launch_bounds__(256) void vq_prep(
        const float* __restrict__ z, const float* __restrict__ cb,
        float* __restrict__ z2w, char* __restrict__ zbi8,
        char* __restrict__ cbbi8, float* __restrict__ loss_out) {
    const int t = threadIdx.x;
    const int bid = blockIdx.x;

    if (bid >= 256) {   // ---- prep_cb: half-panel (64 rows), 4 thr/row
        const int ppi = bid - 256;            // [0,128)
        const int p = ppi >> 1, h = ppi & 1;  // panel, row-half
        const int r = t & 63, qh = t >> 6;    // row-in-half, q-quarter
        const int row = h * 64 + r;           // row in panel [0,128)
        char* dst = cbbi8 + p * 32768;
        const float* src = cb + (p * 128 + row) * 256;
#pragma unroll
        for (int qq = 0; qq < 4; ++qq) {
            const int q = qh * 4 + qq;
            float4 a = *(const float4*)(src + q * 16);
            float4 b = *(const float4*)(src + q * 16 + 4);
            float4 c = *(const float4*)(src + q * 16 + 8);
            float4 d = *(const float4*)(src + q * 16 + 12);
            uint4 v;
            v.x = pk4(q8(a.x,ESCALE), q8(a.y,ESCALE), q8(a.z,ESCALE), q8(a.w,ESCALE));
            v.y = pk4(q8(b.x,ESCALE), q8(b.y,ESCALE), q8(b.z,ESCALE), q8(b.w,ESCALE));
            v.z = pk4(q8(c.x,ESCALE), q8(c.y,ESCALE), q8(c.z,ESCALE), q8(c.w,ESCALE));
            v.w = pk4(q8(d.x,ESCALE), q8(d.y,ESCALE), q8(d.z,ESCALE), q8(d.w,ESCALE));
            *(uint4*)&dst[(q * 128 + row) * 16] = v;
        }
        if (ppi == 0 && t == 0) loss_out[0] = 0.f;
        return;
    }

    // ---- prep_z: 64 rows/block; part = wave: (blk = c-half, jh = j-half)
    __shared__ float pprt[2][64][17];   // jh=1 partials (p4567), padded
    __shared__ float s64[64];
    const int r = t & 63;
    const int part = t >> 6;            // wave index
    const int blk = part >> 1, jh = part & 1;
    const int n = bid * 64 + r;
    const int b = n >> 10, hw = n & 1023;
    const float* base = z + b * 262144 + hw;

    const int p = n >> 7, rp = n & 127;
    char* dst = zbi8 + p * 32768;

    float t0[16], p01[16], pr[16];

#pragma unroll
    for (int jj = 0; jj < 4; ++jj) {
        const int j = jh * 4 + jj;
        float a[16];
#pragma unroll
        for (int L = 0; L < 16; ++L)
            a[L] = base[(blk * 128 + L + 16 * j) * 1024];
        int qb[16];
#pragma unroll
        for (int L = 0; L < 16; ++L) {
            qb[L] = q8(a[L], ZSCALE);
            float sq = a[L] * a[L];
            asm volatile("" : "+v"(sq));   // forbid FMA contraction into adds
            // half-tree: pr = (sq0+sq1) + (sq2+sq3)   (exact v1 association)
            if (jj == 0)      t0[L] = sq;
            else if (jj == 1) p01[L] = t0[L] + sq;
            else if (jj == 2) t0[L] = sq;
            else              pr[L] = p01[L] + (t0[L] + sq);
        }
        uint4 v;
        v.x = pk4(qb[0], qb[1], qb[2], qb[3]);
        v.y = pk4(qb[4], qb[5], qb[6], qb[7]);
        v.z = pk4(qb[8], qb[9], qb[10], qb[11]);
        v.w = pk4(qb[12], qb[13], qb[14], qb[15]);
        *(uint4*)&dst[((blk * 8 + j) * 128 + rp) * 16] = v;
    }

    if (jh == 1) {   // publish p4567 partials
#pragma unroll
        for (int L = 0; L < 16; ++L) pprt[blk][r][L] = pr[L];
    }
    __syncthreads();
    float bs = 0.f;
    if (jh == 0) {   // combine in the validated order: C = p0123 + p4567
        float C[16];
#pragma unroll
        for (int L = 0; L < 16; ++L) C[L] = pr[L] + pprt[blk][r][L];
        float t8[8];
#pragma unroll
        for (int L = 0; L < 8; ++L) t8[L] = C[L] + C[L + 8];
        float t4[4];
#pragma unroll
        for (int L = 0; L < 4; ++L) t4[L] = t8[L] + t8[L + 4];
        float t2a = t4[0] + t4[2];
        float t2b = t4[1] + t4[3];
        bs = t2a + t2b;
        if (blk == 1) s64[r] = bs;
    }
    __syncthreads();
    if (part == 0) z2w[n] = bs + s64[r];   // bs(blk0) + bs(blk1), v1 order
}

// ---------------------------------------------------------------------------
// int8 MFMA screen v10: r4's validated 45.5us structure (grid 8192, one
// z-panel in LDS, ONE staging drain, 1-deep cb prefetch, swapped operands
// mfma(cb,z), lane-local top-2) with a cheaper epilogue:
//  - acc pre-biased: C-in = splat(SBIAS), so pack = one v_lshl_add per score
//    (bit-identical packed value: ((acc+SBIAS)<<6)+col == (acc<<6)+vb+col)
//  - butterfly via v_permlane16/32_swap_b32 (VALU) instead of 16 ds_bpermute
//    (LDS pipe + lgkm waits). Order-agnostic: swap(t,t) gives a register
//    pair whose per-lane SET is {t[l], t[l^d]}; all consumers are max/min
//    of the pair, so which output holds which does not matter.
// Register budget unchanged (64 AGPR + ~64 VGPR, fits the 128 cap of (256,4)).
__global__ __launch_bounds__(256, 4) void vq_gemm(
        const char* __restrict__ zbi8,
        const char* __restrict__ cbbi8,
        unsigned long long* __restrict__ gstats) {
    __shared__ __align__(16) char smem[32768];   // z panel

    const int tid = threadIdx.x;
    const int w = tid >> 6, l = tid & 63;
    const int q4 = l >> 4, cl = l & 15;
    const int mw = w & 1, nw = w >> 1;   // mw: cb 64-half, nw: z 64-half

    // XCD-locality swizzle (validated r5): 16 pm x phased 16 pn per XCD
    const unsigned bx = blockIdx.x;
    const unsigned xcd = bx & 7, local = bx >> 3;
    const unsigned png = local >> 8;
    const unsigned rem = local & 255;
    const unsigned pm = (rem >> 4) * 8 + xcd;
    const unsigned pn = png * 16 + (rem & 15);

    const char* Ab = zbi8 + pm * 32768;
    const char* Bb = cbbi8 + pn * 32768;

    // stage whole z panel: 8 issues x 256 thr x 16B = 32KB
#pragma unroll
    for (int u = 0; u < 8; ++u)
        gload_lds16(Ab + u * 4096 + tid * 16, smem + u * 4096 + (w << 10));

    // cb fragments (MFMA A operand) streamed from L2: row = mw*64+i*16+cl,
    // kchunk = kt*4+q4; i via +256, kt via +8192
    const char* abase = Bb + (q4 * 128 + mw * 64 + cl) * 16;
    v4i af[4], afn[4];
#pragma unroll
    for (int i = 0; i < 4; ++i)
        af[i] = *(const v4i*)(abase + i * 256);

    const unsigned colb = (unsigned)(q4 * 4);   // per-lane col base
    const v4i cinit = (v4i)SBIAS;               // pre-biased accumulator

    v4i acc[4][4];
    __syncthreads();   // single staging drain (af prologue rides along)

#pragma unroll
    for (int kt = 0; kt < 4; ++kt) {
        v4i bfl[4];
#pragma unroll
        for (int j = 0; j < 4; ++j)
            bfl[j] = *(const v4i*)(smem + kt * 8192 + q4 * 2048
                                        + nw * 1024 + j * 256 + cl * 16);
        if (kt < 3) {
#pragma unroll
            for (int i = 0; i < 4; ++i)
                afn[i] = *(const v4i*)(abase + (kt + 1) * 8192 + i * 256);
        }
        __builtin_amdgcn_s_setprio(1);
#pragma unroll
        for (int i = 0; i < 4; ++i)
#pragma unroll
            for (int j = 0; j < 4; ++j) {
                if (kt == 0)
                    acc[i][j] = __builtin_amdgcn_mfma_i32_16x16x64_i8(
                        af[i], bfl[j], cinit, 0, 0, 0);
                else
                    acc[i][j] = __builtin_amdgcn_mfma_i32_16x16x64_i8(
                        af[i], bfl[j], acc[i][j], 0, 0, 0);
            }
        __builtin_amdgcn_s_setprio(0);
#pragma unroll
        for (int i = 0; i < 4; ++i) af[i] = afn[i];
    }

    // ---- epilogue: per z-row lane-local top-2 over this wave's 64 cb -----
    // acc[i][j][g]: cb = mw*64 + i*16 + q4*4 + g, z-row = nw*64 + j*16 + cl
    unsigned long long* gs = gstats + (pn * 2 + (unsigned)mw) * 16384u
                                    + pm * 128u + (unsigned)(nw * 64);
#pragma unroll
    for (int jj = 0; jj < 4; ++jj) {
        unsigned m1[8], m2[8];
#pragma unroll
        for (int i = 0; i < 4; ++i)
#pragma unroll
            for (int gp = 0; gp < 2; ++gp) {
                // pack = (biased acc << 6) | col ; col = q4*4 + i*16 + g
                unsigned pa = ((unsigned)acc[i][jj][2 * gp] << 6)
                              + (colb + (unsigned)(i * 16 + 2 * gp));
                unsigned pb = ((unsigned)acc[i][jj][2 * gp + 1] << 6)
                              + (colb + (unsigned)(i * 16 + 2 * gp + 1));
                m1[i * 2 + gp] = umax_(pa, pb);
                m2[i * 2 + gp] = umin_(pa, pb);
            }
#pragma unroll
        for (int s = 4; s >= 1; s >>= 1)
#pragma unroll
            for (int u = 0; u < 4; ++u) {
                if (u < s) {
                    unsigned a1 = m1[u], a2 = m2[u];
                    unsigned b1 = m1[u + s], b2 = m2[u + s];
                    m1[u] = umax_(a1, b1);
                    m2[u] = umax_(umin_(a1, b1), umax_(a2, b2));
                }
            }
        unsigned t1 = m1[0], t2 = m2[0];
        {   // xor-16 (q4 bit 0) via permlane16_swap: VALU, order-agnostic
            unsigned a1 = t1, b1 = t1, a2 = t2, b2 = t2;
            asm volatile("v_permlane16_swap_b32 %0, %1" : "+v"(a1), "+v"(b1));
            asm volatile("v_permlane16_swap_b32 %0, %1" : "+v"(a2), "+v"(b2));
            t2 = umax_(umin_(a1, b1), umax_(a2, b2));
            t1 = umax_(a1, b1);
        }
        {   // xor-32 (q4 bit 1) via permlane32_swap
            unsigned a1 = t1, b1 = t1, a2 = t2, b2 = t2;
            asm volatile("v_permlane32_swap_b32 %0, %1" : "+v"(a1), "+v"(b1));
            asm volatile("v_permlane32_swap_b32 %0, %1" : "+v"(a2), "+v"(b2));
            t2 = umax_(umin_(a1, b1), umax_(a2, b2));
            t1 = umax_(a1, b1);
        }
        if (q4 == 0)
            gs[jj * 16 + cl] =
                ((unsigned long long)t1 << 32) | (unsigned long long)t2;
    }
}

// ---------------------------------------------------------------------------
// Finalize v3 (VALIDATED r6): rescore + scatter fused, z tile staged ONCE as
// zs[256][32]; barrier-free candidate loop; serial-FMA chain preserved.
__global__ __launch_bounds__(256) void vq_finalize(
        const float* __restrict__ z, const float* __restrict__ cb,
        const float* __restrict__ z2w,
        const unsigned long long* __restrict__ gstats,
        float* __restrict__ out, float* __restrict__ out_idx) {
    __shared__ float zs[256][32];      // [c][r], 32 KB
    __shared__ unsigned pmax[8][32];
    __shared__ int thrL[32];
    __shared__ unsigned candL[512];    // (r<<13)|k
    __shared__ unsigned blkcnt;
    __shared__ unsigned long long bestL[32];
    __shared__ float tile[32 * 257];   // scatter tile, stride 257 floats

    const int t = threadIdx.x;
    const int bid = blockIdx.x;
    const int n0 = bid * 32;
    const int b = bid >> 5, j = bid & 31;
    const int hw0 = j * 32;
    const int r = t & 31, gc = t >> 5;   // gc in [0,8): 16 groups each

    // stage z once: 256 channels x 32 rows, coalesced (128B per 32 lanes)
    {
        const int rr = t & 31, cc2 = t >> 5;
#pragma unroll
        for (int u = 0; u < 32; ++u) {
            int cc = u * 8 + cc2;
            zs[cc][rr] = z[b * 262144 + cc * 1024 + hw0 + rr];
        }
    }

    // phase 1: per-row max of group top1s (= exact global row max); keep e[]
    unsigned long long e[16];
    unsigned m = 0;
#pragma unroll
    for (int g2 = 0; g2 < 16; ++g2) {
        e[g2] = gstats[(size_t)(gc * 16 + g2) * 16384u + (unsigned)(n0 + r)];
        m = umax_(m, (unsigned)(e[g2] >> 32));
    }
    pmax[gc][r] = m;
    if (t == 0) blkcnt = 0;
    __syncthreads();
    if (t < 32) {
        unsigned mm = 0;
#pragma unroll
        for (int g = 0; g < 8; ++g) mm = umax_(mm, pmax[g][t]);
        thrL[t] = (int)(mm >> 6) - MARGIN_INT;   // biased domain both sides
        bestL[t] = ~0ull;
    }
    __syncthreads();

    // phase 2: candidates = group top-1/top-2 entries >= threshold
    {
        int th = thrL[r];
#pragma unroll
        for (int g2 = 0; g2 < 16; ++g2) {
            unsigned p1 = (unsigned)(e[g2] >> 32), p2 = (unsigned)e[g2];
            unsigned kb = (unsigned)(gc * 16 + g2) * 64u;
            if ((int)(p1 >> 6) >= th) {
                unsigned pos = atomicAdd(&blkcnt, 1u);
                if (pos < 512u)
                    candL[pos] = ((unsigned)r << 13) | (kb + (p1 & 63u));
            }
            if ((int)(p2 >> 6) >= th) {
                unsigned pos = atomicAdd(&blkcnt, 1u);
                if (pos < 512u)
                    candL[pos] = ((unsigned)r << 13) | (kb + (p2 & 63u));
            }
        }
    }
    __syncthreads();
    int ns = (int)(blkcnt < 512u ? blkcnt : 512u);

    // rescore: barrier-free candidate loop against the staged zs tile
    for (int base = 0; base < ns; base += 256) {
        if (base + t < ns) {
            unsigned v = candL[base + t];
            int rr0 = v >> 13, k = v & 8191;
            float sacc = 0.f;
#pragma unroll 1
            for (int ch = 0; ch < 8; ++ch) {
                const float4* cbp = (const float4*)(cb + k * 256 + ch * 32);
                float4 A0 = cbp[0], A1 = cbp[1], A2 = cbp[2], A3 = cbp[3];
                float4 A4 = cbp[4], A5 = cbp[5], A6 = cbp[6], A7 = cbp[7];
                float Af[32] = {A0.x,A0.y,A0.z,A0.w, A1.x,A1.y,A1.z,A1.w,
                                A2.x,A2.y,A2.z,A2.w, A3.x,A3.y,A3.z,A3.w,
                                A4.x,A4.y,A4.z,A4.w, A5.x,A5.y,A5.z,A5.w,
                                A6.x,A6.y,A6.z,A6.w, A7.x,A7.y,A7.z,A7.w};
#pragma unroll
                for (int u = 0; u < 32; ++u)
                    sacc = __builtin_fmaf(zs[ch * 32 + u][rr0], Af[u], sacc);
            }
            float d = z2w[n0 + rr0] - 2.0f * sacc;   // single rounding, d > 0
            unsigned long long key =
                ((unsigned long long)__float_as_uint(d) << 32) | (unsigned)k;
            atomicMin(&bestL[rr0], key);
        }
    }
    __syncthreads();
    if (t < 32)
        out_idx[n0 + t] = (float)(unsigned)(bestL[t] & 0xFFFFFFFFu);

    // ---- fused scatter: gather 32 winning cb rows, write out k-coalesced --
    {
        const int c0 = t & 63;
        const int w0 = (t >> 6) * 8;
#pragma unroll
        for (int it = 0; it < 8; ++it) {
            int wr = w0 + it;
            int kk = (int)(unsigned)(bestL[wr] & 0xFFFFFFFFu);
            const float* src = cb + kk * 256 + c0;
            float* drow = tile + wr * 257 + c0;
            drow[0]   = src[0];
            drow[64]  = src[64];
            drow[128] = src[128];
            drow[192] = src[192];
        }
    }
    __syncthreads();

    float* obase = out + b * 262144 + j * 256;
    const int wv = t >> 3, cb8 = (t & 7) * 32;
#pragma unroll
    for (int it = 0; it < 32; ++it)     // it = i; lane = k (coalesced store)
        obase[it * 8192 + t] = tile[wv * 257 + cb8 + it];
}

// ---------------------------------------------------------------------------
// Loss v1 (VALIDATED r6), block = (b, i): z read w-coalesced (staged), out
// re-read coalesced. loss += 1.25/N * sum((zp - zq)^2).
__global__ __launch_bounds__(256) void vq_loss(
        const float* __restrict__ z, const float* __restrict__ out,
        float* __restrict__ loss_out) {
    __shared__ float zs[256][33];
    __shared__ float wsum[4];

    const int t = threadIdx.x;
    const int b = blockIdx.x >> 5, i = blockIdx.x & 31;

#pragma unroll
    for (int it = 0; it < 32; ++it) {
        int k = it * 8 + (t >> 5);
        zs[k][t & 31] = z[b * 262144 + k * 1024 + i * 32 + (t & 31)];
    }
    __syncthreads();

    const float* ob = out + b * 262144 + i * 8192;
    float lsum = 0.f;
#pragma unroll 4
    for (int it = 0; it < 32; ++it) {   // it = j; lane = k
        float d = zs[t][it] - ob[it * 256 + t];
        lsum = __builtin_fmaf(d, d, lsum);
    }
#pragma unroll
    for (int off = 32; off >= 1; off >>= 1) lsum += __shfl_down(lsum, off, 64);
    int lane = t & 63, wv = t >> 6;
    if (lane == 0) wsum[wv] = lsum;
    __syncthreads();
    if (t == 0)
        atomicAdd(loss_out, (wsum[0] + wsum[1] + wsum[2] + wsum[3]) *
                            (1.25f / (float)NELEM));
}

// ---------------------------------------------------------------------------
extern "C" void kernel_launch(void* const* d_in, const int* in_sizes, int n_in,
                              void* d_out, int out_size, void* d_ws, size_t ws_size,
                              hipStream_t stream) {
    const float* z  = (const float*)d_in[0];
    const float* cb = (const float*)d_in[1];
    float* out = (float*)d_out;

    char* ws = (char*)d_ws;
    char* zbi8               = ws;                                   // 4 MB
    char* cbbi8              = ws + 4194304;                         // 2 MB
    unsigned long long* gstats = (unsigned long long*)(ws + 6291456); // 16 MB
    float* z2w               = (float*)(ws + 23068672);

    vq_prep<<<384, 256, 0, stream>>>(z, cb, z2w, zbi8, cbbi8, out + NELEM);

    vq_gemm<<<8192, 256, 0, stream>>>(zbi8, cbbi8, gstats);

    vq_finalize<<<512, 256, 0, stream>>>(z, cb, z2w, gstats,
                                         out, out + NELEM + 1);

    vq_loss<<<512, 256, 0, stream>>>(z, out, out + NELEM);
}

// Round 11
// 141.900 us; speedup vs baseline: 6.5666x; 1.0530x over previous
//
#include <hip/hip_runtime.h>
#include <stdint.h>

// Problem constants
#define NROWS 16384   // B*H*W = 16*32*32
#define KENT  8192    // codebook entries
#define CDIM  256     // embedding dim
#define NELEM 4194304 // B*H*W*C elements of z / z_q

// int8 screen scales: z*22 (clamp +-127 = 5.77 sigma), cb*127*8192 (<=0.5 LSB)
#define ZSCALE 22.0f
#define ESCALE 1040384.0f      // 127*8192, exact in fp32
#define MARGIN_INT 4096        // = 1.79e-4 real ~ 8 sigma of i8-quant error
#define SBIAS 4194304          // 1<<22, |score| <= 256*127*127 = 4129024 < SBIAS

// ws layout (bytes):
//   [0,        4194304): zbi8   i8[4M]   z int8, k-major tile layout
//   [4194304,  6291456): cbi8   i8[2M]   codebook int8, same layout
//   [6291456, 23068672): gstats u64[128][16384]  per (64-entry cb group, row):
//                        (top1 << 32) | top2, packed (score+SBIAS)<<6 | col6
//   [23068672,23134208): z2w   float[16384]  np-tree row norms

typedef int v4i __attribute__((ext_vector_type(4)));

__device__ inline int q8(float x, float s) {
    int v = __float2int_rn(x * s);
    return v < -127 ? -127 : (v > 127 ? 127 : v);
}
__device__ inline unsigned pk4(int a, int b, int c, int d) {
    return (a & 255) | ((b & 255) << 8) | ((c & 255) << 16) | ((d & 255) << 24);
}
__device__ inline unsigned umax_(unsigned a, unsigned b) { return a > b ? a : b; }
__device__ inline unsigned umin_(unsigned a, unsigned b) { return a < b ? a : b; }
__device__ inline void gload_lds16(const void* g, void* l) {
    __builtin_amdgcn_global_load_lds(
        (const __attribute__((address_space(1))) void*)g,
        (__attribute__((address_space(3))) void*)l, 16, 0, 0);
}

// ---------------------------------------------------------------------------
// Fused prep v2 (VALIDATED r4/r6, best measured total): blocks 0..255 =
// prep_z (np-tree z2 + i8 tile, 4 thr/row), blocks 256..383 = prep_cb.
__global__ __launch_bounds__(256) void vq_prep(
        const float* __restrict__ z, const float* __restrict__ cb,
        float* __restrict__ z2w, char* __restrict__ zbi8,
        char* __restrict__ cbbi8, float* __restrict__ loss_out) {
    const int t = threadIdx.x;
    const int bid = blockIdx.x;

    if (bid >= 256) {   // ---- prep_cb: half-panel (64 rows), 4 thr/row
        const int ppi = bid - 256;            // [0,128)
        const int p = ppi >> 1, h = ppi & 1;  // panel, row-half
        const int r = t & 63, qh = t >> 6;    // row-in-half, q-quarter
        const int row = h * 64 + r;           // row in panel [0,128)
        char* dst = cbbi8 + p * 32768;
        const float* src = cb + (p * 128 + row) * 256;
#pragma unroll
        for (int qq = 0; qq < 4; ++qq) {
            const int q = qh * 4 + qq;
            float4 a = *(const float4*)(src + q * 16);
            float4 b = *(const float4*)(src + q * 16 + 4);
            float4 c = *(const float4*)(src + q * 16 + 8);
            float4 d = *(const float4*)(src + q * 16 + 12);
            uint4 v;
            v.x = pk4(q8(a.x,ESCALE), q8(a.y,ESCALE), q8(a.z,ESCALE), q8(a.w,ESCALE));
            v.y = pk4(q8(b.x,ESCALE), q8(b.y,ESCALE), q8(b.z,ESCALE), q8(b.w,ESCALE));
            v.z = pk4(q8(c.x,ESCALE), q8(c.y,ESCALE), q8(c.z,ESCALE), q8(c.w,ESCALE));
            v.w = pk4(q8(d.x,ESCALE), q8(d.y,ESCALE), q8(d.z,ESCALE), q8(d.w,ESCALE));
            *(uint4*)&dst[(q * 128 + row) * 16] = v;
        }
        if (ppi == 0 && t == 0) loss_out[0] = 0.f;
        return;
    }

    // ---- prep_z: 64 rows/block; part = wave: (blk = c-half, jh = j-half)
    __shared__ float pprt[2][64][17];   // jh=1 partials (p4567), padded
    __shared__ float s64[64];
    const int r = t & 63;
    const int part = t >> 6;            // wave index
    const int blk = part >> 1, jh = part & 1;
    const int n = bid * 64 + r;
    const int b = n >> 10, hw = n & 1023;
    const float* base = z + b * 262144 + hw;

    const int p = n >> 7, rp = n & 127;
    char* dst = zbi8 + p * 32768;

    float t0[16], p01[16], pr[16];

#pragma unroll
    for (int jj = 0; jj < 4; ++jj) {
        const int j = jh * 4 + jj;
        float a[16];
#pragma unroll
        for (int L = 0; L < 16; ++L)
            a[L] = base[(blk * 128 + L + 16 * j) * 1024];
        int qb[16];
#pragma unroll
        for (int L = 0; L < 16; ++L) {
            qb[L] = q8(a[L], ZSCALE);
            float sq = a[L] * a[L];
            asm volatile("" : "+v"(sq));   // forbid FMA contraction into adds
            // half-tree: pr = (sq0+sq1) + (sq2+sq3)   (exact v1 association)
            if (jj == 0)      t0[L] = sq;
            else if (jj == 1) p01[L] = t0[L] + sq;
            else if (jj == 2) t0[L] = sq;
            else              pr[L] = p01[L] + (t0[L] + sq);
        }
        uint4 v;
        v.x = pk4(qb[0], qb[1], qb[2], qb[3]);
        v.y = pk4(qb[4], qb[5], qb[6], qb[7]);
        v.z = pk4(qb[8], qb[9], qb[10], qb[11]);
        v.w = pk4(qb[12], qb[13], qb[14], qb[15]);
        *(uint4*)&dst[((blk * 8 + j) * 128 + rp) * 16] = v;
    }

    if (jh == 1) {   // publish p4567 partials
#pragma unroll
        for (int L = 0; L < 16; ++L) pprt[blk][r][L] = pr[L];
    }
    __syncthreads();
    float bs = 0.f;
    if (jh == 0) {   // combine in the validated order: C = p0123 + p4567
        float C[16];
#pragma unroll
        for (int L = 0; L < 16; ++L) C[L] = pr[L] + pprt[blk][r][L];
        float t8[8];
#pragma unroll
        for (int L = 0; L < 8; ++L) t8[L] = C[L] + C[L + 8];
        float t4[4];
#pragma unroll
        for (int L = 0; L < 4; ++L) t4[L] = t8[L] + t8[L + 4];
        float t2a = t4[0] + t4[2];
        float t2b = t4[1] + t4[3];
        bs = t2a + t2b;
        if (blk == 1) s64[r] = bs;
    }
    __syncthreads();
    if (part == 0) z2w[n] = bs + s64[r];   // bs(blk0) + bs(blk1), v1 order
}

// ---------------------------------------------------------------------------
// int8 MFMA screen v11: r4's validated 45.5us structure (grid 8192, one
// z-panel in LDS, ONE staging drain, 1-deep cb prefetch, swapped operands
// mfma(cb,z), lane-local top-2, r4's shfl_xor butterfly) with two cheap,
// validated epilogue cuts:
//  - acc pre-biased: C-in = splat(SBIAS) (validated r9, bit-identical pack)
//  - pack = ONE v_lshl_add_u32 with INLINE tag (i<<4)|g (<=51); the
//    lane-uniform q4*4 column bits are added once per jj AFTER the in-lane
//    tree (adding the same constant to all 16 values preserves order; tag
//    and q4-bits occupy disjoint bit fields, so add == or, still < 64).
// NO permlane asm (r9: +4us, spill signature). Register budget unchanged.
__global__ __launch_bounds__(256, 4) void vq_gemm(
        const char* __restrict__ zbi8,
        const char* __restrict__ cbbi8,
        unsigned long long* __restrict__ gstats) {
    __shared__ __align__(16) char smem[32768];   // z panel

    const int tid = threadIdx.x;
    const int w = tid >> 6, l = tid & 63;
    const int q4 = l >> 4, cl = l & 15;
    const int mw = w & 1, nw = w >> 1;   // mw: cb 64-half, nw: z 64-half

    // XCD-locality swizzle (validated r5): 16 pm x phased 16 pn per XCD
    const unsigned bx = blockIdx.x;
    const unsigned xcd = bx & 7, local = bx >> 3;
    const unsigned png = local >> 8;
    const unsigned rem = local & 255;
    const unsigned pm = (rem >> 4) * 8 + xcd;
    const unsigned pn = png * 16 + (rem & 15);

    const char* Ab = zbi8 + pm * 32768;
    const char* Bb = cbbi8 + pn * 32768;

    // stage whole z panel: 8 issues x 256 thr x 16B = 32KB
#pragma unroll
    for (int u = 0; u < 8; ++u)
        gload_lds16(Ab + u * 4096 + tid * 16, smem + u * 4096 + (w << 10));

    // cb fragments (MFMA A operand) streamed from L2: row = mw*64+i*16+cl,
    // kchunk = kt*4+q4; i via +256, kt via +8192
    const char* abase = Bb + (q4 * 128 + mw * 64 + cl) * 16;
    v4i af[4], afn[4];
#pragma unroll
    for (int i = 0; i < 4; ++i)
        af[i] = *(const v4i*)(abase + i * 256);

    const unsigned colq = (unsigned)(q4 * 4);   // lane-uniform col bits 2..3
    const v4i cinit = (v4i)SBIAS;               // pre-biased accumulator

    v4i acc[4][4];
    __syncthreads();   // single staging drain (af prologue rides along)

#pragma unroll
    for (int kt = 0; kt < 4; ++kt) {
        v4i bfl[4];
#pragma unroll
        for (int j = 0; j < 4; ++j)
            bfl[j] = *(const v4i*)(smem + kt * 8192 + q4 * 2048
                                        + nw * 1024 + j * 256 + cl * 16);
        if (kt < 3) {
#pragma unroll
            for (int i = 0; i < 4; ++i)
                afn[i] = *(const v4i*)(abase + (kt + 1) * 8192 + i * 256);
        }
        __builtin_amdgcn_s_setprio(1);
#pragma unroll
        for (int i = 0; i < 4; ++i)
#pragma unroll
            for (int j = 0; j < 4; ++j) {
                if (kt == 0)
                    acc[i][j] = __builtin_amdgcn_mfma_i32_16x16x64_i8(
                        af[i], bfl[j], cinit, 0, 0, 0);
                else
                    acc[i][j] = __builtin_amdgcn_mfma_i32_16x16x64_i8(
                        af[i], bfl[j], acc[i][j], 0, 0, 0);
            }
        __builtin_amdgcn_s_setprio(0);
#pragma unroll
        for (int i = 0; i < 4; ++i) af[i] = afn[i];
    }

    // ---- epilogue: per z-row lane-local top-2 over this wave's 64 cb -----
    // acc[i][j][g]: cb = mw*64 + i*16 + q4*4 + g, z-row = nw*64 + j*16 + cl
    // pack = (biased acc << 6) | (i<<4) | (q4<<2) | g ; (i<<4)|g is an
    // inline literal; q4<<2 added after the in-lane tree.
    unsigned long long* gs = gstats + (pn * 2 + (unsigned)mw) * 16384u
                                    + pm * 128u + (unsigned)(nw * 64);
#pragma unroll
    for (int jj = 0; jj < 4; ++jj) {
        unsigned m1[8], m2[8];
#pragma unroll
        for (int i = 0; i < 4; ++i)
#pragma unroll
            for (int gp = 0; gp < 2; ++gp) {
                unsigned pa = ((unsigned)acc[i][jj][2 * gp] << 6)
                              + (unsigned)((i << 4) | (2 * gp));
                unsigned pb = ((unsigned)acc[i][jj][2 * gp + 1] << 6)
                              + (unsigned)((i << 4) | (2 * gp + 1));
                m1[i * 2 + gp] = umax_(pa, pb);
                m2[i * 2 + gp] = umin_(pa, pb);
            }
#pragma unroll
        for (int s = 4; s >= 1; s >>= 1)
#pragma unroll
            for (int u = 0; u < 4; ++u) {
                if (u < s) {
                    unsigned a1 = m1[u], a2 = m2[u];
                    unsigned b1 = m1[u + s], b2 = m2[u + s];
                    m1[u] = umax_(a1, b1);
                    m2[u] = umax_(umin_(a1, b1), umax_(a2, b2));
                }
            }
        unsigned t1 = m1[0] + colq, t2 = m2[0] + colq;
#pragma unroll
        for (int off = 16; off <= 32; off <<= 1) {
            unsigned o1 = (unsigned)__shfl_xor((int)t1, off);
            unsigned o2 = (unsigned)__shfl_xor((int)t2, off);
            t2 = umax_(umax_(t2, o2), umin_(t1, o1));
            t1 = umax_(t1, o1);
        }
        if (q4 == 0)
            gs[jj * 16 + cl] =
                ((unsigned long long)t1 << 32) | (unsigned long long)t2;
    }
}

// ---------------------------------------------------------------------------
// Finalize v3 (VALIDATED r6): rescore + scatter fused, z tile staged ONCE as
// zs[256][32]; barrier-free candidate loop; serial-FMA chain preserved.
__global__ __launch_bounds__(256) void vq_finalize(
        const float* __restrict__ z, const float* __restrict__ cb,
        const float* __restrict__ z2w,
        const unsigned long long* __restrict__ gstats,
        float* __restrict__ out, float* __restrict__ out_idx) {
    __shared__ float zs[256][32];      // [c][r], 32 KB
    __shared__ unsigned pmax[8][32];
    __shared__ int thrL[32];
    __shared__ unsigned candL[512];    // (r<<13)|k
    __shared__ unsigned blkcnt;
    __shared__ unsigned long long bestL[32];
    __shared__ float tile[32 * 257];   // scatter tile, stride 257 floats

    const int t = threadIdx.x;
    const int bid = blockIdx.x;
    const int n0 = bid * 32;
    const int b = bid >> 5, j = bid & 31;
    const int hw0 = j * 32;
    const int r = t & 31, gc = t >> 5;   // gc in [0,8): 16 groups each

    // stage z once: 256 channels x 32 rows, coalesced (128B per 32 lanes)
    {
        const int rr = t & 31, cc2 = t >> 5;
#pragma unroll
        for (int u = 0; u < 32; ++u) {
            int cc = u * 8 + cc2;
            zs[cc][rr] = z[b * 262144 + cc * 1024 + hw0 + rr];
        }
    }

    // phase 1: per-row max of group top1s (= exact global row max); keep e[]
    unsigned long long e[16];
    unsigned m = 0;
#pragma unroll
    for (int g2 = 0; g2 < 16; ++g2) {
        e[g2] = gstats[(size_t)(gc * 16 + g2) * 16384u + (unsigned)(n0 + r)];
        m = umax_(m, (unsigned)(e[g2] >> 32));
    }
    pmax[gc][r] = m;
    if (t == 0) blkcnt = 0;
    __syncthreads();
    if (t < 32) {
        unsigned mm = 0;
#pragma unroll
        for (int g = 0; g < 8; ++g) mm = umax_(mm, pmax[g][t]);
        thrL[t] = (int)(mm >> 6) - MARGIN_INT;   // biased domain both sides
        bestL[t] = ~0ull;
    }
    __syncthreads();

    // phase 2: candidates = group top-1/top-2 entries >= threshold
    {
        int th = thrL[r];
#pragma unroll
        for (int g2 = 0; g2 < 16; ++g2) {
            unsigned p1 = (unsigned)(e[g2] >> 32), p2 = (unsigned)e[g2];
            unsigned kb = (unsigned)(gc * 16 + g2) * 64u;
            if ((int)(p1 >> 6) >= th) {
                unsigned pos = atomicAdd(&blkcnt, 1u);
                if (pos < 512u)
                    candL[pos] = ((unsigned)r << 13) | (kb + (p1 & 63u));
            }
            if ((int)(p2 >> 6) >= th) {
                unsigned pos = atomicAdd(&blkcnt, 1u);
                if (pos < 512u)
                    candL[pos] = ((unsigned)r << 13) | (kb + (p2 & 63u));
            }
        }
    }
    __syncthreads();
    int ns = (int)(blkcnt < 512u ? blkcnt : 512u);

    // rescore: barrier-free candidate loop against the staged zs tile
    for (int base = 0; base < ns; base += 256) {
        if (base + t < ns) {
            unsigned v = candL[base + t];
            int rr0 = v >> 13, k = v & 8191;
            float sacc = 0.f;
#pragma unroll 1
            for (int ch = 0; ch < 8; ++ch) {
                const float4* cbp = (const float4*)(cb + k * 256 + ch * 32);
                float4 A0 = cbp[0], A1 = cbp[1], A2 = cbp[2], A3 = cbp[3];
                float4 A4 = cbp[4], A5 = cbp[5], A6 = cbp[6], A7 = cbp[7];
                float Af[32] = {A0.x,A0.y,A0.z,A0.w, A1.x,A1.y,A1.z,A1.w,
                                A2.x,A2.y,A2.z,A2.w, A3.x,A3.y,A3.z,A3.w,
                                A4.x,A4.y,A4.z,A4.w, A5.x,A5.y,A5.z,A5.w,
                                A6.x,A6.y,A6.z,A6.w, A7.x,A7.y,A7.z,A7.w};
#pragma unroll
                for (int u = 0; u < 32; ++u)
                    sacc = __builtin_fmaf(zs[ch * 32 + u][rr0], Af[u], sacc);
            }
            float d = z2w[n0 + rr0] - 2.0f * sacc;   // single rounding, d > 0
            unsigned long long key =
                ((unsigned long long)__float_as_uint(d) << 32) | (unsigned)k;
            atomicMin(&bestL[rr0], key);
        }
    }
    __syncthreads();
    if (t < 32)
        out_idx[n0 + t] = (float)(unsigned)(bestL[t] & 0xFFFFFFFFu);

    // ---- fused scatter: gather 32 winning cb rows, write out k-coalesced --
    {
        const int c0 = t & 63;
        const int w0 = (t >> 6) * 8;
#pragma unroll
        for (int it = 0; it < 8; ++it) {
            int wr = w0 + it;
            int kk = (int)(unsigned)(bestL[wr] & 0xFFFFFFFFu);
            const float* src = cb + kk * 256 + c0;
            float* drow = tile + wr * 257 + c0;
            drow[0]   = src[0];
            drow[64]  = src[64];
            drow[128] = src[128];
            drow[192] = src[192];
        }
    }
    __syncthreads();

    float* obase = out + b * 262144 + j * 256;
    const int wv = t >> 3, cb8 = (t & 7) * 32;
#pragma unroll
    for (int it = 0; it < 32; ++it)     // it = i; lane = k (coalesced store)
        obase[it * 8192 + t] = tile[wv * 257 + cb8 + it];
}

// ---------------------------------------------------------------------------
// Loss v1 (VALIDATED r6), block = (b, i): z read w-coalesced (staged), out
// re-read coalesced. loss += 1.25/N * sum((zp - zq)^2).
__global__ __launch_bounds__(256) void vq_loss(
        const float* __restrict__ z, const float* __restrict__ out,
        float* __restrict__ loss_out) {
    __shared__ float zs[256][33];
    __shared__ float wsum[4];

    const int t = threadIdx.x;
    const int b = blockIdx.x >> 5, i = blockIdx.x & 31;

#pragma unroll
    for (int it = 0; it < 32; ++it) {
        int k = it * 8 + (t >> 5);
        zs[k][t & 31] = z[b * 262144 + k * 1024 + i * 32 + (t & 31)];
    }
    __syncthreads();

    const float* ob = out + b * 262144 + i * 8192;
    float lsum = 0.f;
#pragma unroll 4
    for (int it = 0; it < 32; ++it) {   // it = j; lane = k
        float d = zs[t][it] - ob[it * 256 + t];
        lsum = __builtin_fmaf(d, d, lsum);
    }
#pragma unroll
    for (int off = 32; off >= 1; off >>= 1) lsum += __shfl_down(lsum, off, 64);
    int lane = t & 63, wv = t >> 6;
    if (lane == 0) wsum[wv] = lsum;
    __syncthreads();
    if (t == 0)
        atomicAdd(loss_out, (wsum[0] + wsum[1] + wsum[2] + wsum[3]) *
                            (1.25f / (float)NELEM));
}

// ---------------------------------------------------------------------------
extern "C" void kernel_launch(void* const* d_in, const int* in_sizes, int n_in,
                              void* d_out, int out_size, void* d_ws, size_t ws_size,
                              hipStream_t stream) {
    const float* z  = (const float*)d_in[0];
    const float* cb = (const float*)d_in[1];
    float* out = (float*)d_out;

    char* ws = (char*)d_ws;
    char* zbi8               = ws;                                   // 4 MB
    char* cbbi8              = ws + 4194304;                         // 2 MB
    unsigned long long* gstats = (unsigned long long*)(ws + 6291456); // 16 MB
    float* z2w               = (float*)(ws + 23068672);

    vq_prep<<<384, 256, 0, stream>>>(z, cb, z2w, zbi8, cbbi8, out + NELEM);

    vq_gemm<<<8192, 256, 0, stream>>>(zbi8, cbbi8, gstats);

    vq_finalize<<<512, 256, 0, stream>>>(z, cb, z2w, gstats,
                                         out, out + NELEM + 1);

    vq_loss<<<512, 256, 0, stream>>>(z, out, out + NELEM);
}